// Round 11
// baseline (449.855 us; speedup 1.0000x reference)
//
#include <hip/hip_runtime.h>
#include <float.h>

// Problem constants (fixed by reference: B=8, D=64, H=64, W=64, K=8192)
constexpr int KCODES = 8192;
constexpr int DDIM   = 64;
constexpr int NTOK   = 32768;
constexpr int MT     = 32;                 // tokens per WG (2 sets x 16)
constexpr int KC     = 64;                 // codes per chunk
constexpr int NCH    = KCODES / KC;        // 128 chunks

typedef short v8s __attribute__((ext_vector_type(8)));
typedef unsigned short v16us __attribute__((ext_vector_type(16)));
typedef unsigned short v8us __attribute__((ext_vector_type(8)));
typedef float v4f __attribute__((ext_vector_type(4)));

static __device__ __forceinline__ unsigned short f2bf(float f) {
  union { float f; unsigned u; } v; v.f = f;
  return (unsigned short)((v.u + 0x7fffu + ((v.u >> 16) & 1u)) >> 16);  // RNE
}

// ---- biased half-norms: hn[k] = 0.5*||c_k||^2 + 2.0 (bias keeps phase-1
// scores positive -> fp32 bit pattern monotone for packed-key argmin).
__global__ __launch_bounds__(256) void hn_kernel(
    const float* __restrict__ cb, float* __restrict__ hn) {
  const int c = blockIdx.x;                 // chunk 0..127
  const int tid = threadIdx.x;
  const int g = tid >> 6, lane = tid & 63;
  const int quad = lane >> 4, col = lane & 15;
  const int code = c * KC + g * 16 + col;
  const float* src = cb + (size_t)code * DDIM;
  float sq = 0.f;
#pragma unroll
  for (int ks = 0; ks < 2; ++ks) {
    const float4* p = reinterpret_cast<const float4*>(src + ks * 32 + quad * 8);
    const float4 a = p[0], b = p[1];
    sq += a.x * a.x + a.y * a.y + a.z * a.z + a.w * a.w;
    sq += b.x * b.x + b.y * b.y + b.z * b.z + b.w * b.w;
  }
  sq += __shfl_xor(sq, 16);
  sq += __shfl_xor(sq, 32);
  if (quad == 0) hn[code] = 0.5f * sq + 2.0f;
}

// Phase 1 (SCREEN): hi-only bf16 MFMA, score ~= hn - xh.ch. Codebook is
//   loaded fp32 DIRECTLY from cb (coalesced: 16 rows x 128 B contiguous per
//   wave instruction group) and truncated to bf16 in-register (odd-ushort
//   shuffle -> v_perm). No prep codebook pass, no LDS, no k-loop barriers.
//   4 register buffers / unroll-4 -> load->use distance ~3 compute bodies
//   (>>L2 latency). Screening error e = x.c - xt.ct (B RNE, A truncated):
//   RMS differential ~4e-4, |e| <= ~4e-3 worst-case relevant.
//   Branchless packed-key top-2 per (lane,set) cell:
//   key = (score-bits & ~511) | (it*4 + r); floor quant <= 512 ulp <= 2.4e-4.
// Phase 2: fast path when unique candidate within smin+1e-2. Proof: for a
//   candidate with stored > lim: true > stored - e_max > smin + 1e-2 - 4e-3;
//   smin >= true_min - e_max - 2.4e-4 -> true - true_min > 1e-2 - 8e-3 -
//   2.4e-4 > 1.7e-3 >> numpy's ulp(64) ~1.5e-5 quantization -> numpy cannot
//   prefer it. A numpy-winner distinct from the approx winner is itself
//   within lim -> cnt >= 2 -> refine. Refine = numpy-fp32-faithful decision
//   (pairwise-8 sums, D=fl(fl(S-2p)+N), correctly-rounded-fp64 p,
//   tie -> lowest index) — identical to all passing rounds.
__global__ __launch_bounds__(256, 4) void vq_kernel(
    const float* __restrict__ ze, const float* __restrict__ cb,
    const float* __restrict__ hn, float* __restrict__ out) {
  __shared__ float c_s1[16][MT];   // per-cell best (floored) score
  __shared__ float c_s2[16][MT];
  __shared__ int   c_i1[16][MT];
  __shared__ int   c_i2[16][MT];
  __shared__ int   widx[MT];

  const int tid = threadIdx.x, lane = tid & 63, wv = tid >> 6;
  const int col = lane & 15, quad = lane >> 4;
  const int t0 = blockIdx.x * MT;
  const int bb = t0 >> 12, hw0 = t0 & 4095;   // 4096 % 32 == 0: one batch per WG
  const float* zb = ze + (size_t)bb * (DDIM * 4096) + hw0;

  // ---- B-frags: 2 sets x 16 tokens, negated bf16-hi (RNE), in registers.
  // B[k=(lane>>4)*8+j][n=lane&15]; token = s*16 + col; d = ks*32 + quad*8 + j.
  v8s nxh[2][2];
#pragma unroll
  for (int s = 0; s < 2; ++s) {
    const int mtok = s * 16 + col;
#pragma unroll
    for (int ks = 0; ks < 2; ++ks) {
#pragma unroll
      for (int j = 0; j < 8; ++j) {
        const int d = ks * 32 + quad * 8 + j;
        nxh[s][ks][j] = (short)f2bf(-zb[(size_t)d * 4096 + mtok]);
      }
    }
  }

  // ---- A: direct fp32 codebook loads. Lane (col,quad) covers code
  // it*64 + wv*16 + col, dims {quad*8..+8} and {32+quad*8..+8}.
  const float* base_lane = cb + (size_t)(wv * 16 + col) * DDIM + quad * 8;
  const float* hnp = hn + wv * 16 + quad * 4;

  float4 Ar[4][4];   // [buf][region]: {ks0 lo, ks0 hi, ks1 lo, ks1 hi}
  v4f    hv[4];

  auto loadA = [&](int b, int it) {
    const float4* p = reinterpret_cast<const float4*>(base_lane + (size_t)it * (KC * DDIM));
    Ar[b][0] = p[0];  Ar[b][1] = p[1];    // dims quad*8..+8
    Ar[b][2] = p[8];  Ar[b][3] = p[9];    // dims 32+quad*8..+8
    hv[b] = *reinterpret_cast<const v4f*>(hnp + (size_t)it * KC);
  };

  auto pack = [](const float4 a, const float4 b) -> v8s {   // bf16 truncate x8
    union { float4 f[2]; v16us u; } pk;
    pk.f[0] = a; pk.f[1] = b;
    const v8us o = __builtin_shufflevector(pk.u, pk.u, 1, 3, 5, 7, 9, 11, 13, 15);
    union { v8us u; v8s s; } r; r.u = o;
    return r.s;
  };

  unsigned m1[2] = {0xFFFFFFFFu, 0xFFFFFFFFu};   // packed running top-2 keys
  unsigned m2[2] = {0xFFFFFFFFu, 0xFFFFFFFFu};

  auto compute = [&](int b, int it) {
    const v8s A0 = pack(Ar[b][0], Ar[b][1]);
    const v8s A1 = pack(Ar[b][2], Ar[b][3]);
    v4f acc[2];
#pragma unroll
    for (int s = 0; s < 2; ++s) acc[s] = hv[b];
#pragma unroll
    for (int s = 0; s < 2; ++s)
      acc[s] = __builtin_amdgcn_mfma_f32_16x16x32_bf16(A0, nxh[s][0], acc[s], 0, 0, 0);
#pragma unroll
    for (int s = 0; s < 2; ++s)
      acc[s] = __builtin_amdgcn_mfma_f32_16x16x32_bf16(A1, nxh[s][1], acc[s], 0, 0, 0);

    const unsigned base9 = (unsigned)(it * 4);   // 9-bit cell-local index base
#pragma unroll
    for (int s = 0; s < 2; ++s) {
      unsigned k0 = (__float_as_uint(acc[s][0]) & ~511u) | (base9 + 0);
      unsigned k1 = (__float_as_uint(acc[s][1]) & ~511u) | (base9 + 1);
      unsigned k2 = (__float_as_uint(acc[s][2]) & ~511u) | (base9 + 2);
      unsigned k3 = (__float_as_uint(acc[s][3]) & ~511u) | (base9 + 3);
      const unsigned km = min(min(k0, k1), min(k2, k3));
      const unsigned old1 = m1[s];
      m1[s] = min(old1, km);
      m2[s] = min(m2[s], max(old1, km));   // branchless 2nd-best
    }
  };

  loadA(0, 0); loadA(1, 1); loadA(2, 2); loadA(3, 3);

  for (int it = 0; it < NCH; it += 4) {
    compute(0, it);     if (it + 4 < NCH) loadA(0, it + 4);
    compute(1, it + 1); if (it + 5 < NCH) loadA(1, it + 5);
    compute(2, it + 2); if (it + 6 < NCH) loadA(2, it + 6);
    compute(3, it + 3); if (it + 7 < NCH) loadA(3, it + 7);
  }

  // ---- surface per-cell top-2 (cell = wv*4+quad; 16 cells x 512 codes) ----
  {
    const int cell = wv * 4 + quad;
#pragma unroll
    for (int s = 0; s < 2; ++s) {
      const int m = s * 16 + col;
      const unsigned K1 = m1[s], K2 = m2[s];
      c_s1[cell][m] = __uint_as_float(K1 & ~511u);
      c_s2[cell][m] = __uint_as_float(K2 & ~511u);
      // decode: local = it*4 + r -> code = it*64 + wv*16 + quad*4 + r
      c_i1[cell][m] = (int)((K1 & 511u) >> 2) * KC + wv * 16 + quad * 4 + (int)(K1 & 3u);
      c_i2[cell][m] = (int)((K2 & 511u) >> 2) * KC + wv * 16 + quad * 4 + (int)(K2 & 3u);
    }
  }
  __syncthreads();

  // ---- phase 2: fast path or numpy-faithful refine ----
  if (tid < MT) {
#pragma clang fp contract(off)   // numpy: separate mul then add; no FMA
    const int m = tid;

    float smin = FLT_MAX; int fidx = 0x7fffffff;
    for (int c = 0; c < 16; ++c) {
      const float a = c_s1[c][m];
      if (a < smin) { smin = a; fidx = c_i1[c][m]; }
    }
    const float lim = smin + 1e-2f;   // covers 2*e_screen(4e-3) + key floor
                                      // 2.4e-4 + numpy noise
    int cnt = 0;
    for (int c = 0; c < 16; ++c) {
      cnt += (c_s1[c][m] <= lim);
      cnt += (c_s2[c][m] <= lim);
    }

    int besti;
    if (cnt == 1) {
      besti = fidx;   // unique in-margin candidate: approx argmin == numpy argmin
    } else {
      const float* xz = zb + m;
      float xm[DDIM];
      for (int d = 0; d < DDIM; ++d) xm[d] = xz[(size_t)d * 4096];

      float r[8];
      for (int j = 0; j < 8; ++j) r[j] = xm[j] * xm[j];
      for (int i = 8; i < DDIM; i += 8)
        for (int j = 0; j < 8; ++j) r[j] += xm[i + j] * xm[i + j];
      const float S = ((r[0] + r[1]) + (r[2] + r[3])) + ((r[4] + r[5]) + (r[6] + r[7]));

      float bestD = FLT_MAX;
      besti = 0x7fffffff;
      for (int c = 0; c < 16; ++c) {
        for (int h = 0; h < 2; ++h) {
          const float sp = h ? c_s2[c][m] : c_s1[c][m];
          if (sp > lim) continue;
          const int idx = h ? c_i2[c][m] : c_i1[c][m];
          const float* crow = cb + (size_t)idx * DDIM;

          float rn[8];
          for (int j = 0; j < 8; ++j) rn[j] = crow[j] * crow[j];
          for (int i = 8; i < DDIM; i += 8)
            for (int j = 0; j < 8; ++j) rn[j] += crow[i + j] * crow[i + j];
          const float Nk =
              ((rn[0] + rn[1]) + (rn[2] + rn[3])) + ((rn[4] + rn[5]) + (rn[6] + rn[7]));

          double p64 = 0.0;
          for (int d = 0; d < DDIM; ++d) p64 += (double)xm[d] * (double)crow[d];
          const float pf = (float)p64;

          const float twop = 2.0f * pf;
          const float t1   = S - twop;
          const float Dv   = t1 + Nk;
          if (Dv < bestD || (Dv == bestD && idx < besti)) { bestD = Dv; besti = idx; }
        }
      }
    }
    widx[m] = besti;
  }
  __syncthreads();

  // ---- gather winners, write z_q (32-lane coalesced rows; cb L2-hot) ----
  {
    const int m = tid & 31, dg = tid >> 5;    // dg 0..7
    const int wi = widx[m];
    const float* crow = cb + (size_t)wi * DDIM;
    float* ob = out + (size_t)bb * (DDIM * 4096) + hw0;
#pragma unroll
    for (int p = 0; p < 8; ++p) {
      const int d = dg * 8 + p;
      ob[(size_t)d * 4096 + m] = crow[d];
    }
  }
}

extern "C" void kernel_launch(void* const* d_in, const int* in_sizes, int n_in,
                              void* d_out, int out_size, void* d_ws, size_t ws_size,
                              hipStream_t stream) {
  const float* ze = (const float*)d_in[0];    // [8,64,64,64]
  const float* cb = (const float*)d_in[1];    // [8192,64]
  float* hn = (float*)d_ws;                   // 32 KB biased half-norms
  float* out = (float*)d_out;

  hn_kernel<<<NCH, 256, 0, stream>>>(cb, hn);
  vq_kernel<<<NTOK / MT, 256, 0, stream>>>(ze, cb, hn, out);
}

// Round 12
// 280.018 us; speedup vs baseline: 1.6065x; 1.6065x over previous
//
#include <hip/hip_runtime.h>
#include <float.h>

// Problem constants (fixed by reference: B=8, D=64, H=64, W=64, K=8192)
constexpr int KCODES = 8192;
constexpr int DDIM   = 64;
constexpr int NTOK   = 32768;
constexpr int MT     = 16;                 // tokens per WG (1 set x 16)
constexpr int KC     = 64;                 // codes per chunk
constexpr int NCH    = KCODES / KC;        // 128 chunks
constexpr int CBCHUNK = KC * DDIM * 2;     // 8192 B (64 codes x 64 d x bf16, hi only)

typedef short v8s __attribute__((ext_vector_type(8)));
typedef float v4f __attribute__((ext_vector_type(4)));

static __device__ __forceinline__ unsigned short f2bf(float f) {
  union { float f; unsigned u; } v; v.f = f;
  return (unsigned short)((v.u + 0x7fffu + ((v.u >> 16) & 1u)) >> 16);  // RNE
}

// ---- fused prep: bf16-hi codebook, FRAGMENT-LINEAR for mfma_16x16x32_bf16
// A-operand (A[m=lane&15][k=(lane>>4)*8+j]), + biased half-norms
// hn[k] = 0.5*||c_k||^2 + 2.0 (bias keeps phase-1 scores positive -> fp32
// bit pattern monotone for the packed-key argmin; scores land in [~0.7,~4.5]).
// Per chunk c: byte off = c*8192 + g*2048 + ks*1024 + lane*16 + j*2.
__global__ __launch_bounds__(256) void prep_kernel(
    const float* __restrict__ cb, unsigned short* __restrict__ wcb,
    float* __restrict__ hn) {
  const int c = blockIdx.x;                 // chunk 0..127
  const int tid = threadIdx.x;
  const int g = tid >> 6, lane = tid & 63;
  const int quad = lane >> 4, col = lane & 15;
  const int code = c * KC + g * 16 + col;
  const float* src = cb + (size_t)code * DDIM;
  float sq = 0.f;
#pragma unroll
  for (int ks = 0; ks < 2; ++ks) {
    v8s hi;
#pragma unroll
    for (int j = 0; j < 8; ++j) {
      const float x = src[ks * 32 + quad * 8 + j];
      sq += x * x;
      hi[j] = (short)f2bf(x);
    }
    const size_t b0 = ((size_t)c * CBCHUNK + g * 2048 + ks * 1024 + lane * 16) / 2;
    *reinterpret_cast<v8s*>(wcb + b0) = hi;
  }
  sq += __shfl_xor(sq, 16);
  sq += __shfl_xor(sq, 32);
  if (quad == 0) hn[code] = 0.5f * sq + 2.0f;
}

// Phase 1 (SCREEN): hi-only bf16 MFMA, score ~= hn - xh.ch (err |e|<=~2.8e-3,
//   RMS ~2.5e-4). A-frags register-double-buffered from wcb (coalesced
//   dwordx4, no k-loop barriers, no LDS). MT=16/grid=2048 ->
//   8 WG/CU = 8 waves/SIMD (r10 showed 60% latency stall at 4 waves/SIMD;
//   VGPR<=64 makes 8 feasible — r11's spill disaster at 538 MB WRITE_SIZE
//   taught us to keep prefetch state tiny). Branchless packed-key top-2 per
//   (lane) cell: key = (score-bits & ~511) | (it*4 + r); floor quant
//   <= 512 ulp <= 2.4e-4.
// Phase 2: fast path when unique candidate within smin+8e-3. Proof: for a
//   candidate with stored > lim: true > stored - 2.8e-3; smin >= true_min -
//   2.8e-3 - 2.4e-4 -> true - true_min > 8e-3 - 5.6e-3 - 2.4e-4 > 2e-3 >>
//   numpy's ulp(64) ~1.5e-5 quantization -> numpy cannot prefer it. A
//   numpy-winner distinct from the approx winner is itself within lim ->
//   cnt >= 2 -> refine. Refine = numpy-fp32-faithful decision (pairwise-8
//   sums, D=fl(fl(S-2p)+N), correctly-rounded-fp64 p, tie -> lowest index)
//   — identical to all passing rounds.
__global__ __launch_bounds__(256, 8) void vq_kernel(
    const float* __restrict__ ze, const float* __restrict__ cb,
    const float* __restrict__ hn, const unsigned short* __restrict__ wcb,
    float* __restrict__ out) {
  __shared__ float c_s1[16][MT];   // per-cell best (floored) score
  __shared__ float c_s2[16][MT];
  __shared__ int   c_i1[16][MT];
  __shared__ int   c_i2[16][MT];
  __shared__ int   widx[MT];

  const int tid = threadIdx.x, lane = tid & 63, wv = tid >> 6;
  const int col = lane & 15, quad = lane >> 4;
  const int t0 = blockIdx.x * MT;
  const int bb = t0 >> 12, hw0 = t0 & 4095;   // 4096 % 16 == 0: one batch per WG
  const float* zb = ze + (size_t)bb * (DDIM * 4096) + hw0;

  // ---- B-frag: 16 tokens (shared by all 4 waves), negated bf16-hi (RNE).
  // B[k=(lane>>4)*8+j][n=lane&15]; token = col; d = ks*32 + quad*8 + j.
  v8s nxh[2];
#pragma unroll
  for (int ks = 0; ks < 2; ++ks) {
#pragma unroll
    for (int j = 0; j < 8; ++j) {
      const int d = ks * 32 + quad * 8 + j;
      nxh[ks][j] = (short)f2bf(-zb[(size_t)d * 4096 + col]);
    }
  }

  // ---- A-frag register double buffer; wave wv owns code-group g=wv of each
  // chunk: 2 x 16B coalesced loads per chunk (1 KB term-blocks {ks0, ks1}).
  const char* abase = (const char*)wcb + wv * 2048 + lane * 16;
  const float* hnp  = hn + wv * 16 + quad * 4;

  auto loadA = [&](v8s (&A)[2], v4f& hv, int it) {
    const char* p = abase + (size_t)it * CBCHUNK;
    A[0] = *reinterpret_cast<const v8s*>(p);
    A[1] = *reinterpret_cast<const v8s*>(p + 1024);
    hv = *reinterpret_cast<const v4f*>(hnp + (size_t)it * KC);
  };

  unsigned m1 = 0xFFFFFFFFu, m2 = 0xFFFFFFFFu;   // packed running top-2 keys

  auto compute = [&](const v8s (&A)[2], const v4f hv, int it) {
    v4f acc = hv;
    acc = __builtin_amdgcn_mfma_f32_16x16x32_bf16(A[0], nxh[0], acc, 0, 0, 0);
    acc = __builtin_amdgcn_mfma_f32_16x16x32_bf16(A[1], nxh[1], acc, 0, 0, 0);

    const unsigned base9 = (unsigned)(it * 4);   // 9-bit cell-local index base
    unsigned k0 = (__float_as_uint(acc[0]) & ~511u) | (base9 + 0);
    unsigned k1 = (__float_as_uint(acc[1]) & ~511u) | (base9 + 1);
    unsigned k2 = (__float_as_uint(acc[2]) & ~511u) | (base9 + 2);
    unsigned k3 = (__float_as_uint(acc[3]) & ~511u) | (base9 + 3);
    const unsigned km = min(min(k0, k1), min(k2, k3));
    const unsigned old1 = m1;
    m1 = min(old1, km);
    m2 = min(m2, max(old1, km));   // branchless 2nd-best over chunk-winners
  };

  v8s A0[2], A1[2]; v4f h0, h1;
  loadA(A0, h0, 0); loadA(A1, h1, 1);

  for (int it = 0; it < NCH; it += 2) {
    compute(A0, h0, it);
    if (it + 2 < NCH) loadA(A0, h0, it + 2);
    compute(A1, h1, it + 1);
    if (it + 3 < NCH) loadA(A1, h1, it + 3);
  }

  // ---- surface per-cell top-2 (cell = wv*4+quad; 16 cells x 512 codes) ----
  {
    const int cell = wv * 4 + quad;
    c_s1[cell][col] = __uint_as_float(m1 & ~511u);
    c_s2[cell][col] = __uint_as_float(m2 & ~511u);
    // decode: local = it*4 + r -> code = it*64 + wv*16 + quad*4 + r
    c_i1[cell][col] = (int)((m1 & 511u) >> 2) * KC + wv * 16 + quad * 4 + (int)(m1 & 3u);
    c_i2[cell][col] = (int)((m2 & 511u) >> 2) * KC + wv * 16 + quad * 4 + (int)(m2 & 3u);
  }
  __syncthreads();

  // ---- phase 2: fast path or numpy-faithful refine ----
  if (tid < MT) {
#pragma clang fp contract(off)   // numpy: separate mul then add; no FMA
    const int m = tid;

    float smin = FLT_MAX; int fidx = 0x7fffffff;
    for (int c = 0; c < 16; ++c) {
      const float a = c_s1[c][m];
      if (a < smin) { smin = a; fidx = c_i1[c][m]; }
    }
    const float lim = smin + 8e-3f;   // covers 2*e_screen(2.8e-3) + key floor
                                      // 2.4e-4 + numpy noise, ~1.4x slack
    int cnt = 0;
    for (int c = 0; c < 16; ++c) {
      cnt += (c_s1[c][m] <= lim);
      cnt += (c_s2[c][m] <= lim);
    }

    int besti;
    if (cnt == 1) {
      besti = fidx;   // unique in-margin candidate: approx argmin == numpy argmin
    } else {
      const float* xz = zb + m;
      float xm[DDIM];
      for (int d = 0; d < DDIM; ++d) xm[d] = xz[(size_t)d * 4096];

      float r[8];
      for (int j = 0; j < 8; ++j) r[j] = xm[j] * xm[j];
      for (int i = 8; i < DDIM; i += 8)
        for (int j = 0; j < 8; ++j) r[j] += xm[i + j] * xm[i + j];
      const float S = ((r[0] + r[1]) + (r[2] + r[3])) + ((r[4] + r[5]) + (r[6] + r[7]));

      float bestD = FLT_MAX;
      besti = 0x7fffffff;
      for (int c = 0; c < 16; ++c) {
        for (int h = 0; h < 2; ++h) {
          const float sp = h ? c_s2[c][m] : c_s1[c][m];
          if (sp > lim) continue;
          const int idx = h ? c_i2[c][m] : c_i1[c][m];
          const float* crow = cb + (size_t)idx * DDIM;

          float rn[8];
          for (int j = 0; j < 8; ++j) rn[j] = crow[j] * crow[j];
          for (int i = 8; i < DDIM; i += 8)
            for (int j = 0; j < 8; ++j) rn[j] += crow[i + j] * crow[i + j];
          const float Nk =
              ((rn[0] + rn[1]) + (rn[2] + rn[3])) + ((rn[4] + rn[5]) + (rn[6] + rn[7]));

          double p64 = 0.0;
          for (int d = 0; d < DDIM; ++d) p64 += (double)xm[d] * (double)crow[d];
          const float pf = (float)p64;

          const float twop = 2.0f * pf;
          const float t1   = S - twop;
          const float Dv   = t1 + Nk;
          if (Dv < bestD || (Dv == bestD && idx < besti)) { bestD = Dv; besti = idx; }
        }
      }
    }
    widx[m] = besti;
  }
  __syncthreads();

  // ---- gather winners, write z_q (16-lane coalesced rows; cb L2-hot) ----
  {
    const int m = tid & 15, dg = tid >> 4;    // dg 0..15
    const int wi = widx[m];
    const float* crow = cb + (size_t)wi * DDIM;
    float* ob = out + (size_t)bb * (DDIM * 4096) + hw0;
#pragma unroll
    for (int p = 0; p < 4; ++p) {
      const int d = dg * 4 + p;
      ob[(size_t)d * 4096 + m] = crow[d];
    }
  }
}

extern "C" void kernel_launch(void* const* d_in, const int* in_sizes, int n_in,
                              void* d_out, int out_size, void* d_ws, size_t ws_size,
                              hipStream_t stream) {
  const float* ze = (const float*)d_in[0];    // [8,64,64,64]
  const float* cb = (const float*)d_in[1];    // [8192,64]
  float* hn = (float*)d_ws;                                     // 32 KB
  unsigned short* wcb = (unsigned short*)((char*)d_ws + 32768); // 1 MB frag-linear hi
  float* out = (float*)d_out;

  prep_kernel<<<NCH, 256, 0, stream>>>(cb, wcb, hn);
  vq_kernel<<<NTOK / MT, 256, 0, stream>>>(ze, cb, hn, wcb, out);
}

// Round 13
// 171.241 us; speedup vs baseline: 2.6270x; 1.6352x over previous
//
#include <hip/hip_runtime.h>
#include <float.h>

// Problem constants (fixed by reference: B=8, D=64, H=64, W=64, K=8192)
constexpr int KCODES = 8192;
constexpr int DDIM   = 64;
constexpr int NTOK   = 32768;
constexpr int MT     = 32;                 // tokens per WG (2 sets x 16)
constexpr int KC     = 64;                 // codes per chunk
constexpr int NCH    = KCODES / KC;        // 128 chunks
constexpr int CBCHUNK = KC * DDIM * 2;     // 8192 B (64 codes x 64 d x bf16, hi only)

typedef short v8s __attribute__((ext_vector_type(8)));
typedef float v4f __attribute__((ext_vector_type(4)));

static __device__ __forceinline__ unsigned short f2bf(float f) {
  union { float f; unsigned u; } v; v.f = f;
  return (unsigned short)((v.u + 0x7fffu + ((v.u >> 16) & 1u)) >> 16);  // RNE
}

// ---- fused prep: bf16-hi codebook, FRAGMENT-LINEAR for mfma_16x16x32_bf16
// A-operand (A[m=lane&15][k=(lane>>4)*8+j]), + biased half-norms
// hn[k] = 0.5*||c_k||^2 + 2.0 (bias keeps phase-1 scores positive -> fp32
// bit pattern monotone for the packed-key argmin; scores land in [~0.7,~4.5]).
// Per chunk c: byte off = c*8192 + g*2048 + ks*1024 + lane*16 + j*2.
__global__ __launch_bounds__(256) void prep_kernel(
    const float* __restrict__ cb, unsigned short* __restrict__ wcb,
    float* __restrict__ hn) {
  const int c = blockIdx.x;                 // chunk 0..127
  const int tid = threadIdx.x;
  const int g = tid >> 6, lane = tid & 63;
  const int quad = lane >> 4, col = lane & 15;
  const int code = c * KC + g * 16 + col;
  const float* src = cb + (size_t)code * DDIM;
  float sq = 0.f;
#pragma unroll
  for (int ks = 0; ks < 2; ++ks) {
    v8s hi;
#pragma unroll
    for (int j = 0; j < 8; ++j) {
      const float x = src[ks * 32 + quad * 8 + j];
      sq += x * x;
      hi[j] = (short)f2bf(x);
    }
    const size_t b0 = ((size_t)c * CBCHUNK + g * 2048 + ks * 1024 + lane * 16) / 2;
    *reinterpret_cast<v8s*>(wcb + b0) = hi;
  }
  sq += __shfl_xor(sq, 16);
  sq += __shfl_xor(sq, 32);
  if (quad == 0) hn[code] = 0.5f * sq + 2.0f;
}

// Phase 1 (SCREEN): hi-only bf16 MFMA, score ~= hn - xh.ch (|e|<=~2.8e-3,
//   RMS ~2.5e-4). A-frags register-prefetched from wcb at DISTANCE 4
//   (r10's dist-2 left load->use ~70 cyc << L2 latency ~200-225 cyc ->
//   ~60% stall with all pipes idle; 4 named bf16 buffers = 48 VGPRs of
//   stream state, no spill risk unlike r11's fp32 variant). No k-loop
//   barriers, no LDS. 4 WG/CU (r12 showed forcing 8 waves/SIMD causes
//   VGPR starvation + serialization). Branchless packed-key top-2 per
//   (lane,set) cell: key = (score-bits & ~511) | (it*4 + r); floor quant
//   <= 512 ulp <= 2.4e-4.
// Phase 2: fast path when unique candidate within smin+8e-3. Proof: for a
//   candidate with stored > lim: true > stored - 2.8e-3; smin >= true_min -
//   2.8e-3 - 2.4e-4 -> true - true_min > 8e-3 - 5.6e-3 - 2.4e-4 > 2e-3 >>
//   numpy's ulp(64) ~1.5e-5 quantization -> numpy cannot prefer it. A
//   numpy-winner distinct from the approx winner is itself within lim ->
//   cnt >= 2 -> refine. Refine = numpy-fp32-faithful decision (pairwise-8
//   sums, D=fl(fl(S-2p)+N), correctly-rounded-fp64 p, tie -> lowest index)
//   — identical to all passing rounds.
__global__ __launch_bounds__(256, 4) void vq_kernel(
    const float* __restrict__ ze, const float* __restrict__ cb,
    const float* __restrict__ hn, const unsigned short* __restrict__ wcb,
    float* __restrict__ out) {
  __shared__ float c_s1[16][MT];   // per-cell best (floored) score
  __shared__ float c_s2[16][MT];
  __shared__ int   c_i1[16][MT];
  __shared__ int   c_i2[16][MT];
  __shared__ int   widx[MT];

  const int tid = threadIdx.x, lane = tid & 63, wv = tid >> 6;
  const int col = lane & 15, quad = lane >> 4;
  const int t0 = blockIdx.x * MT;
  const int bb = t0 >> 12, hw0 = t0 & 4095;   // 4096 % 32 == 0: one batch per WG
  const float* zb = ze + (size_t)bb * (DDIM * 4096) + hw0;

  // ---- B-frags: 2 sets x 16 tokens, negated bf16-hi (RNE), in registers.
  // B[k=(lane>>4)*8+j][n=lane&15]; token = s*16 + col; d = ks*32 + quad*8 + j.
  v8s nxh[2][2];
#pragma unroll
  for (int s = 0; s < 2; ++s) {
    const int mtok = s * 16 + col;
#pragma unroll
    for (int ks = 0; ks < 2; ++ks) {
#pragma unroll
      for (int j = 0; j < 8; ++j) {
        const int d = ks * 32 + quad * 8 + j;
        nxh[s][ks][j] = (short)f2bf(-zb[(size_t)d * 4096 + mtok]);
      }
    }
  }

  // ---- A-frag register pipeline (depth 4); wave wv owns code-group g=wv of
  // each chunk: 2 x 16B coalesced loads per chunk (1 KB term-blocks).
  const char* abase = (const char*)wcb + wv * 2048 + lane * 16;
  const float* hnp  = hn + wv * 16 + quad * 4;

  auto loadA = [&](v8s (&A)[2], v4f& hv, int it) {
    const char* p = abase + (size_t)it * CBCHUNK;
    A[0] = *reinterpret_cast<const v8s*>(p);
    A[1] = *reinterpret_cast<const v8s*>(p + 1024);
    hv = *reinterpret_cast<const v4f*>(hnp + (size_t)it * KC);
  };

  unsigned m1[2] = {0xFFFFFFFFu, 0xFFFFFFFFu};   // packed running top-2 keys
  unsigned m2[2] = {0xFFFFFFFFu, 0xFFFFFFFFu};

  auto compute = [&](const v8s (&A)[2], const v4f hv, int it) {
    v4f acc[2];
#pragma unroll
    for (int s = 0; s < 2; ++s) acc[s] = hv;
#pragma unroll
    for (int s = 0; s < 2; ++s)
      acc[s] = __builtin_amdgcn_mfma_f32_16x16x32_bf16(A[0], nxh[s][0], acc[s], 0, 0, 0);
#pragma unroll
    for (int s = 0; s < 2; ++s)
      acc[s] = __builtin_amdgcn_mfma_f32_16x16x32_bf16(A[1], nxh[s][1], acc[s], 0, 0, 0);

    const unsigned base9 = (unsigned)(it * 4);   // 9-bit cell-local index base
#pragma unroll
    for (int s = 0; s < 2; ++s) {
      unsigned k0 = (__float_as_uint(acc[s][0]) & ~511u) | (base9 + 0);
      unsigned k1 = (__float_as_uint(acc[s][1]) & ~511u) | (base9 + 1);
      unsigned k2 = (__float_as_uint(acc[s][2]) & ~511u) | (base9 + 2);
      unsigned k3 = (__float_as_uint(acc[s][3]) & ~511u) | (base9 + 3);
      const unsigned km = min(min(k0, k1), min(k2, k3));
      const unsigned old1 = m1[s];
      m1[s] = min(old1, km);
      m2[s] = min(m2[s], max(old1, km));   // branchless 2nd-best
    }
  };

  v8s A0[2], A1[2], A2[2], A3[2];
  v4f h0, h1, h2, h3;
  loadA(A0, h0, 0); loadA(A1, h1, 1); loadA(A2, h2, 2); loadA(A3, h3, 3);

  for (int it = 0; it < NCH; it += 4) {
    compute(A0, h0, it);     if (it + 4 < NCH) loadA(A0, h0, it + 4);
    compute(A1, h1, it + 1); if (it + 5 < NCH) loadA(A1, h1, it + 5);
    compute(A2, h2, it + 2); if (it + 6 < NCH) loadA(A2, h2, it + 6);
    compute(A3, h3, it + 3); if (it + 7 < NCH) loadA(A3, h3, it + 7);
  }

  // ---- surface per-cell top-2 (cell = wv*4+quad; 16 cells x 512 codes) ----
  {
    const int cell = wv * 4 + quad;
#pragma unroll
    for (int s = 0; s < 2; ++s) {
      const int m = s * 16 + col;
      const unsigned K1 = m1[s], K2 = m2[s];
      c_s1[cell][m] = __uint_as_float(K1 & ~511u);
      c_s2[cell][m] = __uint_as_float(K2 & ~511u);
      // decode: local = it*4 + r -> code = it*64 + wv*16 + quad*4 + r
      c_i1[cell][m] = (int)((K1 & 511u) >> 2) * KC + wv * 16 + quad * 4 + (int)(K1 & 3u);
      c_i2[cell][m] = (int)((K2 & 511u) >> 2) * KC + wv * 16 + quad * 4 + (int)(K2 & 3u);
    }
  }
  __syncthreads();

  // ---- phase 2: fast path or numpy-faithful refine ----
  if (tid < MT) {
#pragma clang fp contract(off)   // numpy: separate mul then add; no FMA
    const int m = tid;

    float smin = FLT_MAX; int fidx = 0x7fffffff;
    for (int c = 0; c < 16; ++c) {
      const float a = c_s1[c][m];
      if (a < smin) { smin = a; fidx = c_i1[c][m]; }
    }
    const float lim = smin + 8e-3f;   // covers 2*e_screen(2.8e-3) + key floor
                                      // 2.4e-4 + numpy noise, ~1.4x slack
    int cnt = 0;
    for (int c = 0; c < 16; ++c) {
      cnt += (c_s1[c][m] <= lim);
      cnt += (c_s2[c][m] <= lim);
    }

    int besti;
    if (cnt == 1) {
      besti = fidx;   // unique in-margin candidate: approx argmin == numpy argmin
    } else {
      const float* xz = zb + m;
      float xm[DDIM];
      for (int d = 0; d < DDIM; ++d) xm[d] = xz[(size_t)d * 4096];

      float r[8];
      for (int j = 0; j < 8; ++j) r[j] = xm[j] * xm[j];
      for (int i = 8; i < DDIM; i += 8)
        for (int j = 0; j < 8; ++j) r[j] += xm[i + j] * xm[i + j];
      const float S = ((r[0] + r[1]) + (r[2] + r[3])) + ((r[4] + r[5]) + (r[6] + r[7]));

      float bestD = FLT_MAX;
      besti = 0x7fffffff;
      for (int c = 0; c < 16; ++c) {
        for (int h = 0; h < 2; ++h) {
          const float sp = h ? c_s2[c][m] : c_s1[c][m];
          if (sp > lim) continue;
          const int idx = h ? c_i2[c][m] : c_i1[c][m];
          const float* crow = cb + (size_t)idx * DDIM;

          float rn[8];
          for (int j = 0; j < 8; ++j) rn[j] = crow[j] * crow[j];
          for (int i = 8; i < DDIM; i += 8)
            for (int j = 0; j < 8; ++j) rn[j] += crow[i + j] * crow[i + j];
          const float Nk =
              ((rn[0] + rn[1]) + (rn[2] + rn[3])) + ((rn[4] + rn[5]) + (rn[6] + rn[7]));

          double p64 = 0.0;
          for (int d = 0; d < DDIM; ++d) p64 += (double)xm[d] * (double)crow[d];
          const float pf = (float)p64;

          const float twop = 2.0f * pf;
          const float t1   = S - twop;
          const float Dv   = t1 + Nk;
          if (Dv < bestD || (Dv == bestD && idx < besti)) { bestD = Dv; besti = idx; }
        }
      }
    }
    widx[m] = besti;
  }
  __syncthreads();

  // ---- gather winners, write z_q (32-lane coalesced rows; cb L2-hot) ----
  {
    const int m = tid & 31, dg = tid >> 5;    // dg 0..7
    const int wi = widx[m];
    const float* crow = cb + (size_t)wi * DDIM;
    float* ob = out + (size_t)bb * (DDIM * 4096) + hw0;
#pragma unroll
    for (int p = 0; p < 8; ++p) {
      const int d = dg * 8 + p;
      ob[(size_t)d * 4096 + m] = crow[d];
    }
  }
}

extern "C" void kernel_launch(void* const* d_in, const int* in_sizes, int n_in,
                              void* d_out, int out_size, void* d_ws, size_t ws_size,
                              hipStream_t stream) {
  const float* ze = (const float*)d_in[0];    // [8,64,64,64]
  const float* cb = (const float*)d_in[1];    // [8192,64]
  float* hn = (float*)d_ws;                                     // 32 KB
  unsigned short* wcb = (unsigned short*)((char*)d_ws + 32768); // 1 MB frag-linear hi
  float* out = (float*)d_out;

  prep_kernel<<<NCH, 256, 0, stream>>>(cb, wcb, hn);
  vq_kernel<<<NTOK / MT, 256, 0, stream>>>(ze, cb, hn, wcb, out);
}